// Round 6
// baseline (308.955 us; speedup 1.0000x reference)
//
#include <hip/hip_runtime.h>

// Problem constants (deterministic from reference _segments()):
//   L_g = 256 + 8g, g=0..31; start_g = 4g(g+63) (4-aligned, NOT 16-aligned);
//   N = 12160 = 95*128. Tile table: T_g = 16g + g*g/4 (16-key tiles); T_32 = 768.
#define NTOT 12160
#define EMBD 512
#define ESMD 1280
#define NHEAD 8
#define HD 64
#define NG 32
#define NTILE 768

typedef __attribute__((ext_vector_type(8))) short short8v;   // 8 bf16 (4 VGPR) MFMA A/B frag
typedef __attribute__((ext_vector_type(4))) short short4v;   // 8 B
typedef __attribute__((ext_vector_type(4))) float floatx4;   // MFMA C/D frag

__device__ inline short f2bf(float f) {
  union { float f; unsigned u; } v; v.f = f;
  unsigned r = v.u + 0x7fffu + ((v.u >> 16) & 1u);   // RNE
  return (short)(r >> 16);
}

// async global->LDS, 16 B per lane. LDS dest = wave-uniform base + lane*16.
__device__ inline void gload_lds16(const void* g, void* l) {
  __builtin_amdgcn_global_load_lds((const __attribute__((address_space(1))) void*)g,
                                   (__attribute__((address_space(3))) void*)l, 16, 0, 0);
}

// node -> graph id. 3969+start_g = (2g+63)^2 exactly (f32-exact, <2^24).
__device__ inline int node_graph(int n) {
  int g = (int)((sqrtf(3969.f + (float)n) - 63.f) * 0.5f);
  if (4 * (g + 1) * (g + 64) <= n) g++;
  else if (4 * g * (g + 63) > n) g--;
  return g;
}

// ---------------- f32 -> bf16 pre-convert (esm + h + 4 small weights) ---------
__global__ __launch_bounds__(256) void cvt_kernel(
    const float* __restrict__ esm, const float* __restrict__ h,
    const float* __restrict__ Wq, const float* __restrict__ Wk,
    const float* __restrict__ Wv, const float* __restrict__ Wo,
    short* __restrict__ esm_b, short* __restrict__ h_b, short* __restrict__ Wq_b,
    short* __restrict__ Wk_b, short* __restrict__ Wv_b, short* __restrict__ Wo_b)
{
  int idx = blockIdx.x * 256 + threadIdx.x;        // 5,709,824 float4 groups exact
  const float* src; short* dst; int off;
  if      (idx < 3891200) { src = esm; dst = esm_b; off = idx; }
  else if (idx < 5447680) { src = h;   dst = h_b;   off = idx - 3891200; }
  else if (idx < 5513216) { src = Wq;  dst = Wq_b;  off = idx - 5447680; }
  else if (idx < 5578752) { src = Wk;  dst = Wk_b;  off = idx - 5513216; }
  else if (idx < 5644288) { src = Wv;  dst = Wv_b;  off = idx - 5578752; }
  else                    { src = Wo;  dst = Wo_b;  off = idx - 5644288; }
  const float4 v = *(const float4*)&src[(size_t)off * 4];
  short4v s; s[0] = f2bf(v.x); s[1] = f2bf(v.y); s[2] = f2bf(v.z); s[3] = f2bf(v.w);
  *(short4v*)&dst[(size_t)off * 4] = s;
}

// ---------------- Wesm [512,1280] f32 -> WesmT [1280,512] bf16 ----------------
__global__ __launch_bounds__(256) void wtrans_kernel(
    const float* __restrict__ W, short* __restrict__ WT)
{
  __shared__ short t[32][33];
  const int c0 = blockIdx.x * 32;      // 1280 axis
  const int r0 = blockIdx.y * 32;      // 512 axis
  const int tr = threadIdx.x >> 5, tc = threadIdx.x & 31;
  for (int i = 0; i < 4; i++)
    t[i * 8 + tr][tc] = f2bf(W[(size_t)(r0 + i * 8 + tr) * 1280 + c0 + tc]);
  __syncthreads();
  for (int i = 0; i < 4; i++)
    WT[(size_t)(c0 + i * 8 + tr) * 512 + r0 + tc] = t[tc][i * 8 + tr];
}

// ------------- bk' = Wk@b_esm + bk ; bv' = Wv@b_esm + bv (f32) ---------------
__global__ __launch_bounds__(256) void bfuse_kernel(
    const float* __restrict__ Wk, const float* __restrict__ Wv,
    const float* __restrict__ besm, const float* __restrict__ bk,
    const float* __restrict__ bv, float* __restrict__ bkp, float* __restrict__ bvp)
{
  int wgid = blockIdx.x * 4 + (threadIdx.x >> 6);   // 1024 waves: 2 mats x 512 rows
  int lane = threadIdx.x & 63;
  const float* W  = (wgid < 512) ? Wk : Wv;
  const float* ba = (wgid < 512) ? bk : bv;
  float* o        = (wgid < 512) ? bkp : bvp;
  int row = wgid & 511;
  const float4 w0 = *(const float4*)&W[(size_t)row * 512 + lane * 8];
  const float4 w1 = *(const float4*)&W[(size_t)row * 512 + lane * 8 + 4];
  const float4 b0 = *(const float4*)&besm[lane * 8];
  const float4 b1 = *(const float4*)&besm[lane * 8 + 4];
  float s = w0.x * b0.x + w0.y * b0.y + w0.z * b0.z + w0.w * b0.w
          + w1.x * b1.x + w1.y * b1.y + w1.z * b1.z + w1.w * b1.w;
  for (int off = 1; off < 64; off <<= 1) s += __shfl_xor(s, off);
  if (lane == 0) o[row] = s + ba[row];
}

// ---------------- GEMM core (256-thread, 128x128): wfuse / o_gemm ------------
// XOR-swizzled LDS (see qkv core). Conflict-free [R5: SQ_LDS_BANK_CONFLICT=0].
__device__ inline void gemm_core(const short* __restrict__ A, const short* __restrict__ W,
                                 int K, int row0, int col0,
                                 short* As, short* Bs, floatx4 acc[4][4])
{
  const int tid = threadIdx.x;
  const int lane = tid & 63, wave = tid >> 6;
  const int l15 = lane & 15, quad = lane >> 4;
  const int wm = (wave >> 1) * 64, wn = (wave & 1) * 64;
  const int lrow = lane >> 3;
  const int scol = ((lane & 7) ^ lrow) * 8;
  const int swz = l15 & 7;

  for (int k0 = 0; k0 < K; k0 += 64) {
    if (k0) __syncthreads();
    for (int p = 0; p < 4; p++) {
      int seg = wave * 4 + p;
      gload_lds16(&A[(size_t)(row0 + seg * 8 + lrow) * K + k0 + scol], &As[seg * 512]);
    }
    for (int p = 0; p < 4; p++) {
      int seg = wave * 4 + p;
      gload_lds16(&W[(size_t)(col0 + seg * 8 + lrow) * K + k0 + scol], &Bs[seg * 512]);
    }
    __syncthreads();
    for (int ks = 0; ks < 64; ks += 32) {
      const int off = (((ks >> 3) + quad) ^ swz) << 3;
      short8v a[4], b[4];
      for (int mt = 0; mt < 4; mt++)
        a[mt] = *(const short8v*)&As[(wm + mt * 16 + l15) * 64 + off];
      for (int nt = 0; nt < 4; nt++)
        b[nt] = *(const short8v*)&Bs[(wn + nt * 16 + l15) * 64 + off];
      for (int mt = 0; mt < 4; mt++)
        for (int nt = 0; nt < 4; nt++)
          acc[mt][nt] = __builtin_amdgcn_mfma_f32_16x16x32_bf16(a[mt], b[nt], acc[mt][nt], 0, 0, 0);
    }
  }
}

// C/D layout: col = lane&15, row = quad*4 + reg  [m89/m91]
__device__ inline void epi_bf16(floatx4 acc[4][4], const float* bias, short* C,
                                int row0, int col0, int wm, int wn, int l15, int quad)
{
  for (int nt = 0; nt < 4; nt++) {
    int col = col0 + wn + nt * 16 + l15;
    float bv = bias[col];
    for (int mt = 0; mt < 4; mt++) {
      int rowb = row0 + wm + mt * 16 + quad * 4;
      for (int r = 0; r < 4; r++)
        C[(size_t)(rowb + r) * EMBD + col] = f2bf(acc[mt][nt][r] + bv);
    }
  }
}

// ------------- wfuse: Wk' = Wk@Wesm, Wv' = Wv@Wesm (bf16, [512,1280]) --------
__global__ __launch_bounds__(256) void wfuse_gemm(
    const short* __restrict__ Wk_b, const short* __restrict__ Wv_b,
    const short* __restrict__ WT, short* __restrict__ Wkp, short* __restrict__ Wvp)
{
  __shared__ short As[128 * 64];
  __shared__ short Bs[128 * 64];
  const int wh = blockIdx.x >= 10;
  const int col0 = (blockIdx.x - (wh ? 10 : 0)) * 128;   // over 1280
  const int row0 = blockIdx.y * 128;                     // over 512
  floatx4 acc[4][4];
  for (int i = 0; i < 4; i++) for (int j = 0; j < 4; j++)
    for (int r = 0; r < 4; r++) acc[i][j][r] = 0.f;
  gemm_core(wh ? Wv_b : Wk_b, WT, 512, row0, col0, As, Bs, acc);
  short* O = wh ? Wvp : Wkp;
  const int lane = threadIdx.x & 63, wave = threadIdx.x >> 6;
  const int l15 = lane & 15, quad = lane >> 4;
  const int wm = (wave >> 1) * 64, wn = (wave & 1) * 64;
  for (int nt = 0; nt < 4; nt++) {
    int col = col0 + wn + nt * 16 + l15;
    for (int mt = 0; mt < 4; mt++) {
      int rowb = row0 + wm + mt * 16 + quad * 4;
      for (int r = 0; r < 4; r++)
        O[(size_t)(rowb + r) * ESMD + col] = f2bf(acc[mt][nt][r]);
    }
  }
}

// ------------- fused Q/K/V GEMM: 128x256 tiles, 8 waves, XCD-pinned rows -----
// Flat grid 576: bid = (r%8) + 8*((r/8)*6 + c). All 6 col-groups of row-block
// r land on XCD r%8 -> per-XCD L2 holds its 12 row-blocks of esm_b (~3.9 MB).
// c: 0,1 -> Q (K=512); 2,3 -> K; 4,5 -> V (K=1280). col0 = (c&1)*256.
// K out packed: elem = ((h*768+ptile)*2+hf)*512 + key16*32 + (dim%32).
// V out packed: elem = ((h*4+dtile)*768+ptile)*256 + dim16*16 + key16.
__global__ __launch_bounds__(512) void qkv_gemm(
    const short* __restrict__ hb, const short* __restrict__ esm_b,
    const short* __restrict__ Wq_b, const short* __restrict__ Wkp, const short* __restrict__ Wvp,
    const float* __restrict__ bq, const float* __restrict__ bkp, const float* __restrict__ bvp,
    short* __restrict__ qb, short* __restrict__ kp, short* __restrict__ vp)
{
  __shared__ short As[128 * 64];    // 16 KB
  __shared__ short Bs[256 * 64];    // 32 KB
  const int bid = blockIdx.x;
  const int xcd = bid & 7, idx = bid >> 3;
  const int rowc = idx / 6, c = idx - rowc * 6;
  const int r = xcd + 8 * rowc;
  if (r >= 95) return;
  const int row0 = r * 128;
  const int col0 = (c & 1) * 256;
  const int which = c >> 1;                        // 0=Q 1=K 2=V
  const short* A = (which == 0) ? hb : esm_b;
  const short* W = (which == 0) ? Wq_b : (which == 1 ? Wkp : Wvp);
  const int K = (which == 0) ? 512 : 1280;

  const int tid = threadIdx.x;
  const int lane = tid & 63, wave = tid >> 6;
  const int l15 = lane & 15, quad = lane >> 4;
  const int wm = (wave >> 2) * 64, wn = (wave & 3) * 64;   // 2M x 4N waves
  const int lrow = lane >> 3;
  const int scol = ((lane & 7) ^ lrow) * 8;
  const int swz = l15 & 7;

  floatx4 acc[4][4];
  for (int i = 0; i < 4; i++) for (int j = 0; j < 4; j++)
    for (int rr = 0; rr < 4; rr++) acc[i][j][rr] = 0.f;

  for (int k0 = 0; k0 < K; k0 += 64) {
    if (k0) __syncthreads();
    for (int p = 0; p < 2; p++) {                  // A: 16 segs, 2/wave
      int seg = wave * 2 + p;
      gload_lds16(&A[(size_t)(row0 + seg * 8 + lrow) * K + k0 + scol], &As[seg * 512]);
    }
    for (int p = 0; p < 4; p++) {                  // B: 32 segs, 4/wave
      int seg = wave * 4 + p;
      gload_lds16(&W[(size_t)(col0 + seg * 8 + lrow) * K + k0 + scol], &Bs[seg * 512]);
    }
    __syncthreads();
    for (int ks = 0; ks < 64; ks += 32) {
      const int off = (((ks >> 3) + quad) ^ swz) << 3;
      short8v a[4], b[4];
      for (int mt = 0; mt < 4; mt++)
        a[mt] = *(const short8v*)&As[(wm + mt * 16 + l15) * 64 + off];
      for (int nt = 0; nt < 4; nt++)
        b[nt] = *(const short8v*)&Bs[(wn + nt * 16 + l15) * 64 + off];
      for (int mt = 0; mt < 4; mt++)
        for (int nt = 0; nt < 4; nt++)
          acc[mt][nt] = __builtin_amdgcn_mfma_f32_16x16x32_bf16(a[mt], b[nt], acc[mt][nt], 0, 0, 0);
    }
  }

  if (which == 0) {
    epi_bf16(acc, bq, qb, row0, col0, wm, wn, l15, quad);
  } else if (which == 1) {                         // K fragment-pack
    for (int mt = 0; mt < 4; mt++) {
      int rowb = row0 + wm + mt * 16 + quad * 4;   // %4 == 0
      int g = node_graph(rowb);
      int loc = rowb - 4 * g * (g + 63);
      int ptile = 16 * g + (g * g) / 4 + (loc >> 4);
      int l15k = loc & 15;                         // + r, no wrap
      for (int nt = 0; nt < 4; nt++) {
        int col = col0 + wn + nt * 16 + l15;
        float bv = bkp[col];
        int hh = col >> 6, dh = col & 63;
        int hfh = dh >> 5, qk = (dh & 31) >> 3, jk = dh & 7;
        size_t base = ((size_t)(hh * NTILE + ptile) * 2 + hfh) * 512
                      + (size_t)l15k * 32 + qk * 8 + jk;
        for (int rr = 0; rr < 4; rr++)
          kp[base + (size_t)rr * 32] = f2bf(acc[mt][nt][rr] + bv);
      }
    }
  } else {                                         // V fragment-pack
    for (int mt = 0; mt < 4; mt++) {
      int rowb = row0 + wm + mt * 16 + quad * 4;
      int g = node_graph(rowb);
      int loc = rowb - 4 * g * (g + 63);
      int ptile = 16 * g + (g * g) / 4 + (loc >> 4);
      int koff = loc & 15;                         // + r, no wrap (%4==0)
      for (int nt = 0; nt < 4; nt++) {
        int col = col0 + wn + nt * 16 + l15;
        float bv = bvp[col];
        int hh = col >> 6, dh = col & 63;
        int dt = dh >> 4, l15v = dh & 15;
        size_t base = ((size_t)(hh * 4 + dt) * NTILE + ptile) * 256
                      + (size_t)l15v * 16 + koff;
        short4v sv;
        for (int rr = 0; rr < 4; rr++) sv[rr] = f2bf(acc[mt][nt][rr] + bv);
        *(short4v*)&vp[base] = sv;
      }
    }
  }
}

// ------------- attention: packed-fragment loads (all hot loads 1KB contig) ---
template<bool MASK>
__device__ inline void attn_chunk(
    int kc, int L, int Tg, int hb, int hdt4,
    const short* __restrict__ kp, const short* __restrict__ vp,
    short* Ps, const short8v& aq0, const short8v& aq1,
    floatx4 oacc[4], float rowsum[4], int l15, int quad)
{
  floatx4 s[4];
  const int t0 = Tg + (kc >> 4);
  for (int sub = 0; sub < 4; sub++) {
    const short* kpt = &kp[((size_t)(hb + t0 + sub) * 2) * 512 + l15 * 32 + quad * 8];
    short8v b0 = *(const short8v*)kpt;
    short8v b1 = *(const short8v*)(kpt + 512);
    floatx4 c; for (int r = 0; r < 4; r++) c[r] = 0.f;
    c = __builtin_amdgcn_mfma_f32_16x16x32_bf16(aq0, b0, c, 0, 0, 0);
    c = __builtin_amdgcn_mfma_f32_16x16x32_bf16(aq1, b1, c, 0, 0, 0);
    s[sub] = c;
  }
  for (int sub = 0; sub < 4; sub++)
    for (int r = 0; r < 4; r++) {
      float p = __expf(s[sub][r] * 0.125f);
      if (MASK && (kc + sub * 16 + l15 >= L)) p = 0.f;
      rowsum[r] += p;
      Ps[(quad * 4 + r) * 72 + sub * 16 + l15] = f2bf(p);
    }
  for (int half = 0; half < 2; half++) {
    short8v pA = *(const short8v*)&Ps[l15 * 72 + half * 32 + quad * 8];
    for (int dt = 0; dt < 4; dt++) {
      size_t vbase = ((size_t)(hdt4 + dt) * NTILE + t0 + half * 2 + (quad >> 1)) * 256
                     + (size_t)l15 * 16 + (quad & 1) * 8;
      short8v bvv = *(const short8v*)&vp[vbase];
      oacc[dt] = __builtin_amdgcn_mfma_f32_16x16x32_bf16(pA, bvv, oacc[dt], 0, 0, 0);
    }
  }
}

__global__ __launch_bounds__(512) void attn_kernel(
    const short* __restrict__ qb, const short* __restrict__ kp,
    const short* __restrict__ vp, short* __restrict__ ao)
{
  __shared__ short Ps_all[8][16 * 72];
  const int x = blockIdx.x & 7, j = blockIdx.x >> 3;
  int g = -1, qt = 0, accum = 0;
  for (int i = 0; i < 4; i++) {                 // graphs x, x+8, x+16, x+24
    int gg = x + 8 * i;
    int t = 16 + ((gg + 1) >> 1);               // ceil(L_g/16)
    if (j < accum + t) { g = gg; qt = j - accum; break; }
    accum += t;
  }
  if (g < 0) return;
  const int L = 256 + 8 * g;
  const int start = 4 * g * (g + 63);
  const int Tg = 16 * g + (g * g) / 4;
  const int h = threadIdx.x >> 6;               // wave = head
  const int lane = threadIdx.x & 63;
  const int l15 = lane & 15, quad = lane >> 4;
  const int hb = h * NTILE, hdt4 = h * 4;
  short* Ps = Ps_all[h];

  int qrow = qt * 16 + l15;
  if (qrow > L - 1) qrow = L - 1;
  const size_t qoff = (size_t)(start + qrow) * EMBD + h * HD + quad * 8;
  const short8v aq0 = *(const short8v*)&qb[qoff];
  const short8v aq1 = *(const short8v*)&qb[qoff + 32];

  float rowsum[4];
  floatx4 oacc[4];
  for (int r = 0; r < 4; r++) rowsum[r] = 0.f;
  for (int dt = 0; dt < 4; dt++)
    for (int r = 0; r < 4; r++) oacc[dt][r] = 0.f;

  const int Lfull = L & ~63;
  for (int kc = 0; kc < Lfull; kc += 64)
    attn_chunk<false>(kc, L, Tg, hb, hdt4, kp, vp, Ps, aq0, aq1, oacc, rowsum, l15, quad);
  if (Lfull < L)
    attn_chunk<true>(Lfull, L, Tg, hb, hdt4, kp, vp, Ps, aq0, aq1, oacc, rowsum, l15, quad);

  float inv[4];
  for (int r = 0; r < 4; r++) {
    float red = rowsum[r];
    red += __shfl_xor(red, 1); red += __shfl_xor(red, 2);
    red += __shfl_xor(red, 4); red += __shfl_xor(red, 8);
    inv[r] = 1.f / red;
  }
  for (int dt = 0; dt < 4; dt++)
    for (int r = 0; r < 4; r++) {
      int rl = qt * 16 + quad * 4 + r;
      if (rl < L)
        ao[(size_t)(start + rl) * EMBD + h * HD + dt * 16 + l15] = f2bf(oacc[dt][r] * inv[r]);
    }
}

__global__ __launch_bounds__(256) void o_gemm(
    const short* __restrict__ A, const short* __restrict__ W,
    const float* __restrict__ bias, float* __restrict__ C)
{
  __shared__ short As[128 * 64];
  __shared__ short Bs[128 * 64];
  floatx4 acc[4][4];
  for (int i = 0; i < 4; i++) for (int j = 0; j < 4; j++)
    for (int r = 0; r < 4; r++) acc[i][j][r] = 0.f;
  const int row0 = blockIdx.y * 128, col0 = blockIdx.x * 128;
  gemm_core(A, W, EMBD, row0, col0, As, Bs, acc);
  const int lane = threadIdx.x & 63, wave = threadIdx.x >> 6;
  const int l15 = lane & 15, quad = lane >> 4;
  const int wm = (wave >> 1) * 64, wn = (wave & 1) * 64;
  for (int nt = 0; nt < 4; nt++) {
    int col = col0 + wn + nt * 16 + l15;
    float bv = bias[col];
    for (int mt = 0; mt < 4; mt++) {
      int rowb = row0 + wm + mt * 16 + quad * 4;
      for (int r = 0; r < 4; r++)
        C[(size_t)(rowb + r) * EMBD + col] = acc[mt][nt][r] + bv;
    }
  }
}

// y (= d_out f32) <- LayerNorm(y + h) * gamma + beta, in place
__global__ __launch_bounds__(64) void ln_kernel(
    float* __restrict__ y, const float* __restrict__ hres,
    const float* __restrict__ gamma, const float* __restrict__ beta)
{
  const int row = blockIdx.x;
  const int lane = threadIdx.x;
  const size_t base = (size_t)row * EMBD + lane * 8;
  const float4 a0 = *(const float4*)&y[base];
  const float4 a1 = *(const float4*)&y[base + 4];
  const float4 b0 = *(const float4*)&hres[base];
  const float4 b1 = *(const float4*)&hres[base + 4];
  float x[8] = { a0.x + b0.x, a0.y + b0.y, a0.z + b0.z, a0.w + b0.w,
                 a1.x + b1.x, a1.y + b1.y, a1.z + b1.z, a1.w + b1.w };
  float s = 0.f, s2 = 0.f;
  for (int i = 0; i < 8; i++) { s += x[i]; s2 += x[i] * x[i]; }
  for (int off = 1; off < 64; off <<= 1) { s += __shfl_xor(s, off); s2 += __shfl_xor(s2, off); }
  const float mu = s * (1.f / 512.f);
  const float var = s2 * (1.f / 512.f) - mu * mu;
  const float rstd = rsqrtf(var + 1e-5f);
  const float4 g0 = *(const float4*)&gamma[lane * 8];
  const float4 g1 = *(const float4*)&gamma[lane * 8 + 4];
  const float4 e0 = *(const float4*)&beta[lane * 8];
  const float4 e1 = *(const float4*)&beta[lane * 8 + 4];
  const float gg[8] = { g0.x, g0.y, g0.z, g0.w, g1.x, g1.y, g1.z, g1.w };
  const float ee[8] = { e0.x, e0.y, e0.z, e0.w, e1.x, e1.y, e1.z, e1.w };
  float o[8];
  for (int i = 0; i < 8; i++) o[i] = (x[i] - mu) * rstd * gg[i] + ee[i];
  *(float4*)&y[base]     = make_float4(o[0], o[1], o[2], o[3]);
  *(float4*)&y[base + 4] = make_float4(o[4], o[5], o[6], o[7]);
}

extern "C" void kernel_launch(void* const* d_in, const int* in_sizes, int n_in,
                              void* d_out, int out_size, void* d_ws, size_t ws_size,
                              hipStream_t stream)
{
  (void)in_sizes; (void)n_in; (void)out_size; (void)ws_size;
  const float* esm   = (const float*)d_in[0];
  const float* h     = (const float*)d_in[1];
  const float* Wesm  = (const float*)d_in[2];
  const float* besm  = (const float*)d_in[3];
  const float* Wq    = (const float*)d_in[4];
  const float* bq    = (const float*)d_in[5];
  const float* Wk    = (const float*)d_in[6];
  const float* bk    = (const float*)d_in[7];
  const float* Wv    = (const float*)d_in[8];
  const float* bv    = (const float*)d_in[9];
  const float* Wo    = (const float*)d_in[10];
  const float* bo    = (const float*)d_in[11];
  const float* gamma = (const float*)d_in[12];
  const float* beta  = (const float*)d_in[13];

  // ws layout (bytes), total 61,018,112:
  //   esm_b [0, 31129600)                 dead after qkv -> ao aliases it
  //   kp    [31129600, 43712512)          WesmT aliases kp base (dead first)
  //   vp    [43712512, 56295424)
  //   Wq_b  [56295424, +512K) Wk_b Wv_b Wo_b (each 524288)
  //   Wkp   [58392576, +1310720)  Wvp [59703296, +1310720)
  //   bkp   [61014016, +2048)     bvp [61016064, +2048)
  // d_out: qb [0, 12451840) | h_b [12451840, 24903680) — both dead by o_gemm
  char* ws = (char*)d_ws;
  short* esm_b  = (short*)ws;
  short* ao     = esm_b;
  short* kp     = (short*)(ws + 31129600);
  short* WesmT  = kp;
  short* vp     = (short*)(ws + 43712512);
  short* Wq_b   = (short*)(ws + 56295424);
  short* Wk_b   = (short*)(ws + 56819712);
  short* Wv_b   = (short*)(ws + 57344000);
  short* Wo_b   = (short*)(ws + 57868288);
  short* Wkp    = (short*)(ws + 58392576);
  short* Wvp    = (short*)(ws + 59703296);
  float* bkp    = (float*)(ws + 61014016);
  float* bvp    = (float*)(ws + 61016064);
  short* qb     = (short*)d_out;
  short* h_b    = (short*)((char*)d_out + 12451840);
  float* y      = (float*)d_out;

  cvt_kernel<<<dim3(22304), dim3(256), 0, stream>>>(
      esm, h, Wq, Wk, Wv, Wo, esm_b, h_b, Wq_b, Wk_b, Wv_b, Wo_b);
  wtrans_kernel<<<dim3(40, 16), dim3(256), 0, stream>>>(Wesm, WesmT);
  bfuse_kernel<<<dim3(256), dim3(256), 0, stream>>>(Wk, Wv, besm, bk, bv, bkp, bvp);
  wfuse_gemm<<<dim3(20, 4), dim3(256), 0, stream>>>(Wk_b, Wv_b, WesmT, Wkp, Wvp);
  qkv_gemm<<<dim3(576), dim3(512), 0, stream>>>(
      h_b, esm_b, Wq_b, Wkp, Wvp, bq, bkp, bvp, qb, kp, vp);
  attn_kernel<<<dim3(832), dim3(512), 0, stream>>>(qb, kp, vp, ao);
  o_gemm<<<dim3(4, 95), dim3(256), 0, stream>>>(ao, Wo_b, bo, y);
  ln_kernel<<<dim3(NTOT), dim3(64), 0, stream>>>(y, h, gamma, beta);
}

// Round 7
// 297.302 us; speedup vs baseline: 1.0392x; 1.0392x over previous
//
#include <hip/hip_runtime.h>

// Problem constants (deterministic from reference _segments()):
//   L_g = 256 + 8g, g=0..31; start_g = 4g(g+63) (4-aligned, NOT 16-aligned);
//   N = 12160 = 95*128. Tile table: T_g = 16g + g*g/4 (16-key tiles); T_32 = 768.
#define NTOT 12160
#define EMBD 512
#define ESMD 1280
#define NHEAD 8
#define HD 64
#define NG 32
#define NTILE 768

typedef __attribute__((ext_vector_type(8))) short short8v;   // 8 bf16 (4 VGPR) MFMA A/B frag
typedef __attribute__((ext_vector_type(4))) short short4v;   // 8 B
typedef __attribute__((ext_vector_type(4))) float floatx4;   // MFMA C/D frag

__device__ inline short f2bf(float f) {
  union { float f; unsigned u; } v; v.f = f;
  unsigned r = v.u + 0x7fffu + ((v.u >> 16) & 1u);   // RNE
  return (short)(r >> 16);
}

// async global->LDS, 16 B per lane. LDS dest = wave-uniform base + lane*16.
__device__ inline void gload_lds16(const void* g, void* l) {
  __builtin_amdgcn_global_load_lds((const __attribute__((address_space(1))) void*)g,
                                   (__attribute__((address_space(3))) void*)l, 16, 0, 0);
}

// node -> graph id. 3969+start_g = (2g+63)^2 exactly (f32-exact, <2^24).
__device__ inline int node_graph(int n) {
  int g = (int)((sqrtf(3969.f + (float)n) - 63.f) * 0.5f);
  if (4 * (g + 1) * (g + 64) <= n) g++;
  else if (4 * g * (g + 63) > n) g--;
  return g;
}

// ---------- prep: cvt(esm,h,W*) + wtrans + bfuse, one launch, block ranges ----
__global__ __launch_bounds__(256) void prep_kernel(
    const float* __restrict__ esm, const float* __restrict__ h,
    const float* __restrict__ Wesm, const float* __restrict__ besm,
    const float* __restrict__ Wq, const float* __restrict__ Wk,
    const float* __restrict__ Wv, const float* __restrict__ Wo,
    const float* __restrict__ bk, const float* __restrict__ bv,
    short* __restrict__ esm_b, short* __restrict__ h_b, short* __restrict__ Wq_b,
    short* __restrict__ Wk_b, short* __restrict__ Wv_b, short* __restrict__ Wo_b,
    short* __restrict__ WT, float* __restrict__ bkp, float* __restrict__ bvp)
{
  const int b = blockIdx.x;
  if (b < 22304) {                               // f32 -> bf16 convert
    int idx = b * 256 + threadIdx.x;             // 5,709,824 float4 groups exact
    const float* src; short* dst; int off;
    if      (idx < 3891200) { src = esm; dst = esm_b; off = idx; }
    else if (idx < 5447680) { src = h;   dst = h_b;   off = idx - 3891200; }
    else if (idx < 5513216) { src = Wq;  dst = Wq_b;  off = idx - 5447680; }
    else if (idx < 5578752) { src = Wk;  dst = Wk_b;  off = idx - 5513216; }
    else if (idx < 5644288) { src = Wv;  dst = Wv_b;  off = idx - 5578752; }
    else                    { src = Wo;  dst = Wo_b;  off = idx - 5644288; }
    const float4 v = *(const float4*)&src[(size_t)off * 4];
    short4v s; s[0] = f2bf(v.x); s[1] = f2bf(v.y); s[2] = f2bf(v.z); s[3] = f2bf(v.w);
    *(short4v*)&dst[(size_t)off * 4] = s;
  } else if (b < 22944) {                        // Wesm [512,1280] -> WT [1280,512] bf16
    __shared__ short t[32][33];
    const int bb = b - 22304;
    const int c0 = (bb % 40) * 32, r0 = (bb / 40) * 32;
    const int tr = threadIdx.x >> 5, tc = threadIdx.x & 31;
    for (int i = 0; i < 4; i++)
      t[i * 8 + tr][tc] = f2bf(Wesm[(size_t)(r0 + i * 8 + tr) * 1280 + c0 + tc]);
    __syncthreads();
    for (int i = 0; i < 4; i++)
      WT[(size_t)(c0 + i * 8 + tr) * 512 + r0 + tc] = t[tc][i * 8 + tr];
  } else {                                       // bk' = Wk@besm + bk; bv' likewise
    int wgid = (b - 22944) * 4 + (threadIdx.x >> 6);
    int lane = threadIdx.x & 63;
    const float* W  = (wgid < 512) ? Wk : Wv;
    const float* ba = (wgid < 512) ? bk : bv;
    float* o        = (wgid < 512) ? bkp : bvp;
    int row = wgid & 511;
    const float4 w0 = *(const float4*)&W[(size_t)row * 512 + lane * 8];
    const float4 w1 = *(const float4*)&W[(size_t)row * 512 + lane * 8 + 4];
    const float4 b0 = *(const float4*)&besm[lane * 8];
    const float4 b1 = *(const float4*)&besm[lane * 8 + 4];
    float s = w0.x * b0.x + w0.y * b0.y + w0.z * b0.z + w0.w * b0.w
            + w1.x * b1.x + w1.y * b1.y + w1.z * b1.z + w1.w * b1.w;
    for (int off = 1; off < 64; off <<= 1) s += __shfl_xor(s, off);
    if (lane == 0) o[row] = s + ba[row];
  }
}

// -------- GEMM core (256-thr, 128x128), double-buffered, 1 barrier/iter ------
// XOR-swizzled LDS (conflict-free, R5: SQ_LDS_BANK_CONFLICT=0). Prefetch of
// tile k+1 issues BEFORE compute(k): the next barrier's vmcnt(0) drain waits
// on loads that had a full compute phase to land.
// As/Bs are [2][128*64] (32 KB each).
__device__ inline void gemm_core(const short* __restrict__ A, const short* __restrict__ W,
                                 int K, int row0, int col0,
                                 short* As, short* Bs, floatx4 acc[4][4])
{
  const int tid = threadIdx.x;
  const int lane = tid & 63, wave = tid >> 6;
  const int l15 = lane & 15, quad = lane >> 4;
  const int wm = (wave >> 1) * 64, wn = (wave & 1) * 64;
  const int lrow = lane >> 3;
  const int scol = ((lane & 7) ^ lrow) * 8;
  const int swz = l15 & 7;
  const int niter = K >> 6;

  for (int p = 0; p < 4; p++) {                  // stage tile 0 into buf 0
    int seg = wave * 4 + p;
    gload_lds16(&A[(size_t)(row0 + seg * 8 + lrow) * K + scol], &As[seg * 512]);
    gload_lds16(&W[(size_t)(col0 + seg * 8 + lrow) * K + scol], &Bs[seg * 512]);
  }
  for (int it = 0; it < niter; it++) {
    const int cur = (it & 1) * 8192;
    __syncthreads();                             // staging of cur complete
    if (it + 1 < niter) {
      const int nxt = ((it + 1) & 1) * 8192;
      const int k0 = (it + 1) << 6;
      for (int p = 0; p < 4; p++) {
        int seg = wave * 4 + p;
        gload_lds16(&A[(size_t)(row0 + seg * 8 + lrow) * K + k0 + scol], &As[nxt + seg * 512]);
        gload_lds16(&W[(size_t)(col0 + seg * 8 + lrow) * K + k0 + scol], &Bs[nxt + seg * 512]);
      }
    }
    for (int ks = 0; ks < 64; ks += 32) {
      const int off = (((ks >> 3) + quad) ^ swz) << 3;
      short8v a[4], b[4];
      for (int mt = 0; mt < 4; mt++)
        a[mt] = *(const short8v*)&As[cur + (wm + mt * 16 + l15) * 64 + off];
      for (int nt = 0; nt < 4; nt++)
        b[nt] = *(const short8v*)&Bs[cur + (wn + nt * 16 + l15) * 64 + off];
      for (int mt = 0; mt < 4; mt++)
        for (int nt = 0; nt < 4; nt++)
          acc[mt][nt] = __builtin_amdgcn_mfma_f32_16x16x32_bf16(a[mt], b[nt], acc[mt][nt], 0, 0, 0);
    }
  }
}

// C/D layout: col = lane&15, row = quad*4 + reg  [m89/m91]
__device__ inline void epi_bf16(floatx4 acc[4][4], const float* bias, short* C,
                                int row0, int col0, int wm, int wn, int l15, int quad)
{
  for (int nt = 0; nt < 4; nt++) {
    int col = col0 + wn + nt * 16 + l15;
    float bv = bias[col];
    for (int mt = 0; mt < 4; mt++) {
      int rowb = row0 + wm + mt * 16 + quad * 4;
      for (int r = 0; r < 4; r++)
        C[(size_t)(rowb + r) * EMBD + col] = f2bf(acc[mt][nt][r] + bv);
    }
  }
}

// ------------- wfuse: Wk' = Wk@Wesm, Wv' = Wv@Wesm (bf16, [512,1280]) --------
__global__ __launch_bounds__(256) void wfuse_gemm(
    const short* __restrict__ Wk_b, const short* __restrict__ Wv_b,
    const short* __restrict__ WT, short* __restrict__ Wkp, short* __restrict__ Wvp)
{
  __shared__ short As[2 * 128 * 64];
  __shared__ short Bs[2 * 128 * 64];
  const int wh = blockIdx.x >= 10;
  const int col0 = (blockIdx.x - (wh ? 10 : 0)) * 128;   // over 1280
  const int row0 = blockIdx.y * 128;                     // over 512
  floatx4 acc[4][4];
  for (int i = 0; i < 4; i++) for (int j = 0; j < 4; j++)
    for (int r = 0; r < 4; r++) acc[i][j][r] = 0.f;
  gemm_core(wh ? Wv_b : Wk_b, WT, 512, row0, col0, As, Bs, acc);
  short* O = wh ? Wvp : Wkp;
  const int lane = threadIdx.x & 63, wave = threadIdx.x >> 6;
  const int l15 = lane & 15, quad = lane >> 4;
  const int wm = (wave >> 1) * 64, wn = (wave & 1) * 64;
  for (int nt = 0; nt < 4; nt++) {
    int col = col0 + wn + nt * 16 + l15;
    for (int mt = 0; mt < 4; mt++) {
      int rowb = row0 + wm + mt * 16 + quad * 4;
      for (int r = 0; r < 4; r++)
        O[(size_t)(rowb + r) * ESMD + col] = f2bf(acc[mt][nt][r]);
    }
  }
}

// ------- fused Q/K/V GEMM: 128x256 tiles, 8 waves, XCD-pinned, dbuf LDS ------
// bid = (r%8) + 8*((r/8)*6 + c): all 6 col-groups of row-block r on XCD r%8.
// c: 0,1 -> Q (K=512); 2,3 -> K; 4,5 -> V (K=1280). col0 = (c&1)*256.
__global__ __launch_bounds__(512) void qkv_gemm(
    const short* __restrict__ hb, const short* __restrict__ esm_b,
    const short* __restrict__ Wq_b, const short* __restrict__ Wkp, const short* __restrict__ Wvp,
    const float* __restrict__ bq, const float* __restrict__ bkp, const float* __restrict__ bvp,
    short* __restrict__ qb, short* __restrict__ kp, short* __restrict__ vp)
{
  __shared__ short As[2 * 128 * 64];    // 32 KB
  __shared__ short Bs[2 * 256 * 64];    // 64 KB
  const int bid = blockIdx.x;
  const int xcd = bid & 7, idx = bid >> 3;
  const int rowc = idx / 6, c = idx - rowc * 6;
  const int r = xcd + 8 * rowc;
  if (r >= 95) return;
  const int row0 = r * 128;
  const int col0 = (c & 1) * 256;
  const int which = c >> 1;                        // 0=Q 1=K 2=V
  const short* A = (which == 0) ? hb : esm_b;
  const short* W = (which == 0) ? Wq_b : (which == 1 ? Wkp : Wvp);
  const int K = (which == 0) ? 512 : 1280;

  const int tid = threadIdx.x;
  const int lane = tid & 63, wave = tid >> 6;
  const int l15 = lane & 15, quad = lane >> 4;
  const int wm = (wave >> 2) * 64, wn = (wave & 3) * 64;   // 2M x 4N waves
  const int lrow = lane >> 3;
  const int scol = ((lane & 7) ^ lrow) * 8;
  const int swz = l15 & 7;
  const int niter = K >> 6;

  floatx4 acc[4][4];
  for (int i = 0; i < 4; i++) for (int j = 0; j < 4; j++)
    for (int rr = 0; rr < 4; rr++) acc[i][j][rr] = 0.f;

  for (int p = 0; p < 2; p++) {                    // stage tile 0 -> buf 0
    int seg = wave * 2 + p;
    gload_lds16(&A[(size_t)(row0 + seg * 8 + lrow) * K + scol], &As[seg * 512]);
  }
  for (int p = 0; p < 4; p++) {
    int seg = wave * 4 + p;
    gload_lds16(&W[(size_t)(col0 + seg * 8 + lrow) * K + scol], &Bs[seg * 512]);
  }
  for (int it = 0; it < niter; it++) {
    const int curA = (it & 1) * 8192, curB = (it & 1) * 16384;
    __syncthreads();
    if (it + 1 < niter) {
      const int nxtA = ((it + 1) & 1) * 8192, nxtB = ((it + 1) & 1) * 16384;
      const int k0 = (it + 1) << 6;
      for (int p = 0; p < 2; p++) {
        int seg = wave * 2 + p;
        gload_lds16(&A[(size_t)(row0 + seg * 8 + lrow) * K + k0 + scol], &As[nxtA + seg * 512]);
      }
      for (int p = 0; p < 4; p++) {
        int seg = wave * 4 + p;
        gload_lds16(&W[(size_t)(col0 + seg * 8 + lrow) * K + k0 + scol], &Bs[nxtB + seg * 512]);
      }
    }
    for (int ks = 0; ks < 64; ks += 32) {
      const int off = (((ks >> 3) + quad) ^ swz) << 3;
      short8v a[4], b[4];
      for (int mt = 0; mt < 4; mt++)
        a[mt] = *(const short8v*)&As[curA + (wm + mt * 16 + l15) * 64 + off];
      for (int nt = 0; nt < 4; nt++)
        b[nt] = *(const short8v*)&Bs[curB + (wn + nt * 16 + l15) * 64 + off];
      for (int mt = 0; mt < 4; mt++)
        for (int nt = 0; nt < 4; nt++)
          acc[mt][nt] = __builtin_amdgcn_mfma_f32_16x16x32_bf16(a[mt], b[nt], acc[mt][nt], 0, 0, 0);
    }
  }

  if (which == 0) {
    epi_bf16(acc, bq, qb, row0, col0, wm, wn, l15, quad);
  } else if (which == 1) {                         // K fragment-pack
    for (int mt = 0; mt < 4; mt++) {
      int rowb = row0 + wm + mt * 16 + quad * 4;   // %4 == 0
      int g = node_graph(rowb);
      int loc = rowb - 4 * g * (g + 63);
      int ptile = 16 * g + (g * g) / 4 + (loc >> 4);
      int l15k = loc & 15;                         // + r, no wrap
      for (int nt = 0; nt < 4; nt++) {
        int col = col0 + wn + nt * 16 + l15;
        float bv = bkp[col];
        int hh = col >> 6, dh = col & 63;
        int hfh = dh >> 5, qk = (dh & 31) >> 3, jk = dh & 7;
        size_t base = ((size_t)(hh * NTILE + ptile) * 2 + hfh) * 512
                      + (size_t)l15k * 32 + qk * 8 + jk;
        for (int rr = 0; rr < 4; rr++)
          kp[base + (size_t)rr * 32] = f2bf(acc[mt][nt][rr] + bv);
      }
    }
  } else {                                         // V fragment-pack
    for (int mt = 0; mt < 4; mt++) {
      int rowb = row0 + wm + mt * 16 + quad * 4;
      int g = node_graph(rowb);
      int loc = rowb - 4 * g * (g + 63);
      int ptile = 16 * g + (g * g) / 4 + (loc >> 4);
      int koff = loc & 15;                         // + r, no wrap (%4==0)
      for (int nt = 0; nt < 4; nt++) {
        int col = col0 + wn + nt * 16 + l15;
        float bv = bvp[col];
        int hh = col >> 6, dh = col & 63;
        int dt = dh >> 4, l15v = dh & 15;
        size_t base = ((size_t)(hh * 4 + dt) * NTILE + ptile) * 256
                      + (size_t)l15v * 16 + koff;
        short4v sv;
        for (int rr = 0; rr < 4; rr++) sv[rr] = f2bf(acc[mt][nt][rr] + bv);
        *(short4v*)&vp[base] = sv;
      }
    }
  }
}

// -------- attention: 2 q-tiles per wave (K/V frags feed 2 MFMAs each) --------
template<bool MASK>
__device__ inline void attn_chunk2(
    int kc, int L, int Tg, int hb, int hdt4,
    const short* __restrict__ kp, const short* __restrict__ vp,
    short* Ps, const short8v aq0[2], const short8v aq1[2],
    floatx4 oacc[2][4], float rowsum[2][4], int l15, int quad)
{
  floatx4 s[2][4];
  const int t0 = Tg + (kc >> 4);
  for (int sub = 0; sub < 4; sub++) {
    const short* kpt = &kp[((size_t)(hb + t0 + sub) * 2) * 512 + l15 * 32 + quad * 8];
    short8v b0 = *(const short8v*)kpt;
    short8v b1 = *(const short8v*)(kpt + 512);
    for (int q = 0; q < 2; q++) {
      floatx4 cc; for (int r = 0; r < 4; r++) cc[r] = 0.f;
      cc = __builtin_amdgcn_mfma_f32_16x16x32_bf16(aq0[q], b0, cc, 0, 0, 0);
      cc = __builtin_amdgcn_mfma_f32_16x16x32_bf16(aq1[q], b1, cc, 0, 0, 0);
      s[q][sub] = cc;
    }
  }
  for (int q = 0; q < 2; q++)
    for (int sub = 0; sub < 4; sub++)
      for (int r = 0; r < 4; r++) {
        float p = __expf(s[q][sub][r] * 0.125f);
        if (MASK && (kc + sub * 16 + l15 >= L)) p = 0.f;
        rowsum[q][r] += p;
        Ps[q * 1152 + (quad * 4 + r) * 72 + sub * 16 + l15] = f2bf(p);
      }
  for (int half = 0; half < 2; half++) {
    short8v pA[2];
    for (int q = 0; q < 2; q++)
      pA[q] = *(const short8v*)&Ps[q * 1152 + l15 * 72 + half * 32 + quad * 8];
    for (int dt = 0; dt < 4; dt++) {
      size_t vbase = ((size_t)(hdt4 + dt) * NTILE + t0 + half * 2 + (quad >> 1)) * 256
                     + (size_t)l15 * 16 + (quad & 1) * 8;
      short8v bvv = *(const short8v*)&vp[vbase];
      for (int q = 0; q < 2; q++)
        oacc[q][dt] = __builtin_amdgcn_mfma_f32_16x16x32_bf16(pA[q], bvv, oacc[q][dt], 0, 0, 0);
    }
  }
}

__global__ __launch_bounds__(512) void attn_kernel(
    const short* __restrict__ qb, const short* __restrict__ kp,
    const short* __restrict__ vp, short* __restrict__ ao)
{
  __shared__ short Ps_all[8][2][16 * 72];       // 36,864 B
  const int x = blockIdx.x & 7, j = blockIdx.x >> 3;
  int g = -1, p2 = 0, accum = 0;
  for (int i = 0; i < 4; i++) {                 // graphs x, x+8, x+16, x+24
    int gg = x + 8 * i;
    int tq = 16 + ((gg + 1) >> 1);              // ceil(L/16)
    int tp = (tq + 1) >> 1;                     // q-tile pairs
    if (j < accum + tp) { g = gg; p2 = j - accum; break; }
    accum += tp;
  }
  if (g < 0) return;
  const int L = 256 + 8 * g;
  const int start = 4 * g * (g + 63);
  const int Tg = 16 * g + (g * g) / 4;
  const int T = 16 + ((g + 1) >> 1);
  const int h = threadIdx.x >> 6;               // wave = head
  const int lane = threadIdx.x & 63;
  const int l15 = lane & 15, quad = lane >> 4;
  const int hb = h * NTILE, hdt4 = h * 4;
  short* Ps = &Ps_all[h][0][0];

  int qt[2];
  qt[0] = 2 * p2;
  qt[1] = min(2 * p2 + 1, T - 1);               // duplicate tile: benign double-store
  short8v aq0[2], aq1[2];
  for (int q = 0; q < 2; q++) {
    int qrow = qt[q] * 16 + l15;
    if (qrow > L - 1) qrow = L - 1;
    const size_t qoff = (size_t)(start + qrow) * EMBD + h * HD + quad * 8;
    aq0[q] = *(const short8v*)&qb[qoff];
    aq1[q] = *(const short8v*)&qb[qoff + 32];
  }

  float rowsum[2][4];
  floatx4 oacc[2][4];
  for (int q = 0; q < 2; q++)
    for (int r = 0; r < 4; r++) { rowsum[q][r] = 0.f;
      for (int dt = 0; dt < 4; dt++) oacc[q][dt][r] = 0.f; }

  const int Lfull = L & ~63;
  for (int kc = 0; kc < Lfull; kc += 64)
    attn_chunk2<false>(kc, L, Tg, hb, hdt4, kp, vp, Ps, aq0, aq1, oacc, rowsum, l15, quad);
  if (Lfull < L)
    attn_chunk2<true>(Lfull, L, Tg, hb, hdt4, kp, vp, Ps, aq0, aq1, oacc, rowsum, l15, quad);

  for (int q = 0; q < 2; q++) {
    float inv[4];
    for (int r = 0; r < 4; r++) {
      float red = rowsum[q][r];
      red += __shfl_xor(red, 1); red += __shfl_xor(red, 2);
      red += __shfl_xor(red, 4); red += __shfl_xor(red, 8);
      inv[r] = 1.f / red;
    }
    for (int dt = 0; dt < 4; dt++)
      for (int r = 0; r < 4; r++) {
        int rl = qt[q] * 16 + quad * 4 + r;
        if (rl < L)
          ao[(size_t)(start + rl) * EMBD + h * HD + dt * 16 + l15] = f2bf(oacc[q][dt][r] * inv[r]);
      }
  }
}

__global__ __launch_bounds__(256) void o_gemm(
    const short* __restrict__ A, const short* __restrict__ W,
    const float* __restrict__ bias, float* __restrict__ C)
{
  __shared__ short As[2 * 128 * 64];
  __shared__ short Bs[2 * 128 * 64];
  floatx4 acc[4][4];
  for (int i = 0; i < 4; i++) for (int j = 0; j < 4; j++)
    for (int r = 0; r < 4; r++) acc[i][j][r] = 0.f;
  const int row0 = blockIdx.y * 128, col0 = blockIdx.x * 128;
  gemm_core(A, W, EMBD, row0, col0, As, Bs, acc);
  const int lane = threadIdx.x & 63, wave = threadIdx.x >> 6;
  const int l15 = lane & 15, quad = lane >> 4;
  const int wm = (wave >> 1) * 64, wn = (wave & 1) * 64;
  for (int nt = 0; nt < 4; nt++) {
    int col = col0 + wn + nt * 16 + l15;
    float bv = bias[col];
    for (int mt = 0; mt < 4; mt++) {
      int rowb = row0 + wm + mt * 16 + quad * 4;
      for (int r = 0; r < 4; r++)
        C[(size_t)(rowb + r) * EMBD + col] = acc[mt][nt][r] + bv;
    }
  }
}

// y (= d_out f32) <- LayerNorm(y + h) * gamma + beta, in place
__global__ __launch_bounds__(64) void ln_kernel(
    float* __restrict__ y, const float* __restrict__ hres,
    const float* __restrict__ gamma, const float* __restrict__ beta)
{
  const int row = blockIdx.x;
  const int lane = threadIdx.x;
  const size_t base = (size_t)row * EMBD + lane * 8;
  const float4 a0 = *(const float4*)&y[base];
  const float4 a1 = *(const float4*)&y[base + 4];
  const float4 b0 = *(const float4*)&hres[base];
  const float4 b1 = *(const float4*)&hres[base + 4];
  float x[8] = { a0.x + b0.x, a0.y + b0.y, a0.z + b0.z, a0.w + b0.w,
                 a1.x + b1.x, a1.y + b1.y, a1.z + b1.z, a1.w + b1.w };
  float s = 0.f, s2 = 0.f;
  for (int i = 0; i < 8; i++) { s += x[i]; s2 += x[i] * x[i]; }
  for (int off = 1; off < 64; off <<= 1) { s += __shfl_xor(s, off); s2 += __shfl_xor(s2, off); }
  const float mu = s * (1.f / 512.f);
  const float var = s2 * (1.f / 512.f) - mu * mu;
  const float rstd = rsqrtf(var + 1e-5f);
  const float4 g0 = *(const float4*)&gamma[lane * 8];
  const float4 g1 = *(const float4*)&gamma[lane * 8 + 4];
  const float4 e0 = *(const float4*)&beta[lane * 8];
  const float4 e1 = *(const float4*)&beta[lane * 8 + 4];
  const float gg[8] = { g0.x, g0.y, g0.z, g0.w, g1.x, g1.y, g1.z, g1.w };
  const float ee[8] = { e0.x, e0.y, e0.z, e0.w, e1.x, e1.y, e1.z, e1.w };
  float o[8];
  for (int i = 0; i < 8; i++) o[i] = (x[i] - mu) * rstd * gg[i] + ee[i];
  *(float4*)&y[base]     = make_float4(o[0], o[1], o[2], o[3]);
  *(float4*)&y[base + 4] = make_float4(o[4], o[5], o[6], o[7]);
}

extern "C" void kernel_launch(void* const* d_in, const int* in_sizes, int n_in,
                              void* d_out, int out_size, void* d_ws, size_t ws_size,
                              hipStream_t stream)
{
  (void)in_sizes; (void)n_in; (void)out_size; (void)ws_size;
  const float* esm   = (const float*)d_in[0];
  const float* h     = (const float*)d_in[1];
  const float* Wesm  = (const float*)d_in[2];
  const float* besm  = (const float*)d_in[3];
  const float* Wq    = (const float*)d_in[4];
  const float* bq    = (const float*)d_in[5];
  const float* Wk    = (const float*)d_in[6];
  const float* bk    = (const float*)d_in[7];
  const float* Wv    = (const float*)d_in[8];
  const float* bv    = (const float*)d_in[9];
  const float* Wo    = (const float*)d_in[10];
  const float* bo    = (const float*)d_in[11];
  const float* gamma = (const float*)d_in[12];
  const float* beta  = (const float*)d_in[13];

  // ws layout (bytes), total 61,018,112:
  //   esm_b [0, 31129600)                 dead after qkv -> ao aliases it
  //   kp    [31129600, 43712512)          WesmT aliases kp base (dead first)
  //   vp    [43712512, 56295424)
  //   Wq_b  [56295424, +512K) Wk_b Wv_b Wo_b (each 524288)
  //   Wkp   [58392576, +1310720)  Wvp [59703296, +1310720)
  //   bkp   [61014016, +2048)     bvp [61016064, +2048)
  // d_out: qb [0, 12451840) | h_b [12451840, 24903680) — both dead by o_gemm
  char* ws = (char*)d_ws;
  short* esm_b  = (short*)ws;
  short* ao     = esm_b;
  short* kp     = (short*)(ws + 31129600);
  short* WesmT  = kp;
  short* vp     = (short*)(ws + 43712512);
  short* Wq_b   = (short*)(ws + 56295424);
  short* Wk_b   = (short*)(ws + 56819712);
  short* Wv_b   = (short*)(ws + 57344000);
  short* Wo_b   = (short*)(ws + 57868288);
  short* Wkp    = (short*)(ws + 58392576);
  short* Wvp    = (short*)(ws + 59703296);
  float* bkp    = (float*)(ws + 61014016);
  float* bvp    = (float*)(ws + 61016064);
  short* qb     = (short*)d_out;
  short* h_b    = (short*)((char*)d_out + 12451840);
  float* y      = (float*)d_out;

  prep_kernel<<<dim3(23200), dim3(256), 0, stream>>>(
      esm, h, Wesm, besm, Wq, Wk, Wv, Wo, bk, bv,
      esm_b, h_b, Wq_b, Wk_b, Wv_b, Wo_b, WesmT, bkp, bvp);
  wfuse_gemm<<<dim3(20, 4), dim3(256), 0, stream>>>(Wk_b, Wv_b, WesmT, Wkp, Wvp);
  qkv_gemm<<<dim3(576), dim3(512), 0, stream>>>(
      h_b, esm_b, Wq_b, Wkp, Wvp, bq, bkp, bvp, qb, kp, vp);
  attn_kernel<<<dim3(416), dim3(512), 0, stream>>>(qb, kp, vp, ao);
  o_gemm<<<dim3(4, 95), dim3(256), 0, stream>>>(ao, Wo_b, bo, y);
  ln_kernel<<<dim3(NTOT), dim3(64), 0, stream>>>(y, h, gamma, beta);
}